// Round 2
// baseline (437.720 us; speedup 1.0000x reference)
//
#include <hip/hip_runtime.h>
#include <stdint.h>

#define M_DIM 8192
#define K_DIM 4096
#define N_DIM 4096
#define BM 128
#define BN 128
#define BK 64

typedef __attribute__((ext_vector_type(4))) int i32x4;

// ---------------------------------------------------------------------------
// Pack int32 (values in [-128,127]) -> int8.
// Each thread: ONE contiguous int4 load (16B/lane -> 1KiB/wave coalesced),
// one 4B store (256B/wave). Grid-stride, 2048 blocks.
// (R1 version loaded 4x int4 with 64B/lane stride -> 64 cachelines per
//  instruction -> ~1 TB/s effective. This version is transaction-optimal.)
// ---------------------------------------------------------------------------
__global__ __launch_bounds__(256) void pack_kernel(const int* __restrict__ src,
                                                   int8_t* __restrict__ dst,
                                                   int n4) {
  const int stride = gridDim.x * 256;
  for (int i = blockIdx.x * 256 + threadIdx.x; i < n4; i += stride) {
    int4 v = reinterpret_cast<const int4*>(src)[i];
    int p = (v.x & 0xff) | ((v.y & 0xff) << 8) |
            ((v.z & 0xff) << 16) | ((v.w & 0xff) << 24);
    reinterpret_cast<int*>(dst)[i] = p;
  }
}

// Writes the second tuple output (out_scale) at out[M*N].
__global__ void tail_kernel(float* __restrict__ out, const float* __restrict__ so) {
  out[(size_t)M_DIM * N_DIM] = so[0];
}

// ---------------------------------------------------------------------------
// m97-structure int8 GEMM: 128x128 tile, BK=64, 4 waves (2x2), each wave owns
// a 64x64 sub-tile = 4x4 fragments of 16x16, mfma_i32_16x16x64_i8.
// A: [M,K] int8 row-major.  B: [N,K] int8 row-major (i.e. B^T, like A).
// UNCHANGED from the passing R1 kernel (isolating the pack fix this round).
// ---------------------------------------------------------------------------
template <bool DIRECT>
__global__ __launch_bounds__(256) void gemm_kernel(
    const int8_t* __restrict__ A8, const int8_t* __restrict__ B8,
    const int* __restrict__ A32, const int* __restrict__ B32,
    float* __restrict__ out,
    const float* __restrict__ sx, const float* __restrict__ sw,
    const float* __restrict__ so) {
  __shared__ int8_t As[BM * BK];  // 8 KiB, row-major [row][k], 64 B/row
  __shared__ int8_t Bs[BN * BK];  // 8 KiB, row-major [col][k]

  const int tid = threadIdx.x;
  const int lane = tid & 63;
  const int wid = tid >> 6;
  const int bid = blockIdx.x;
  const int bm = bid % (M_DIM / BM);  // consecutive bids share the B tile
  const int bn = bid / (M_DIM / BM);
  const size_t arow0 = (size_t)bm * BM;
  const size_t bcol0 = (size_t)bn * BN;

  const int wrr = wid >> 1;   // wave row (0..1) -> 64-row strip
  const int wcc = wid & 1;    // wave col (0..1) -> 64-col strip
  const int lrow = lane & 15; // row (A) / col (B) within 16x16 fragment
  const int kq = lane >> 4;   // k-quarter: 16 bytes at kq*16

  i32x4 acc[4][4] = {};

  for (int kk = 0; kk < K_DIM; kk += BK) {
    if constexpr (!DIRECT) {
#pragma unroll
      for (int i = 0; i < 2; ++i) {
        int loff = i * 4096 + tid * 16;  // lane-linear LDS byte offset
        int r = loff >> 6, c = loff & 63;
        __builtin_amdgcn_global_load_lds(
            (const __attribute__((address_space(1))) void*)(A8 + (arow0 + r) * K_DIM + kk + c),
            (__attribute__((address_space(3))) void*)(As + loff), 16, 0, 0);
        __builtin_amdgcn_global_load_lds(
            (const __attribute__((address_space(1))) void*)(B8 + (bcol0 + r) * K_DIM + kk + c),
            (__attribute__((address_space(3))) void*)(Bs + loff), 16, 0, 0);
      }
    } else {
#pragma unroll
      for (int i = 0; i < 2; ++i) {
        int loff = i * 4096 + tid * 16;
        int r = loff >> 6, c = loff & 63;
        const int4* a4 = reinterpret_cast<const int4*>(A32 + (arow0 + r) * K_DIM + kk + c);
        const int4* b4 = reinterpret_cast<const int4*>(B32 + (bcol0 + r) * K_DIM + kk + c);
        int4 a0 = a4[0], a1 = a4[1], a2 = a4[2], a3 = a4[3];
        int4 b0 = b4[0], b1 = b4[1], b2 = b4[2], b3 = b4[3];
        int4 pa, pb;
        pa.x = (a0.x & 0xff) | ((a0.y & 0xff) << 8) | ((a0.z & 0xff) << 16) | ((a0.w & 0xff) << 24);
        pa.y = (a1.x & 0xff) | ((a1.y & 0xff) << 8) | ((a1.z & 0xff) << 16) | ((a1.w & 0xff) << 24);
        pa.z = (a2.x & 0xff) | ((a2.y & 0xff) << 8) | ((a2.z & 0xff) << 16) | ((a2.w & 0xff) << 24);
        pa.w = (a3.x & 0xff) | ((a3.y & 0xff) << 8) | ((a3.z & 0xff) << 16) | ((a3.w & 0xff) << 24);
        pb.x = (b0.x & 0xff) | ((b0.y & 0xff) << 8) | ((b0.z & 0xff) << 16) | ((b0.w & 0xff) << 24);
        pb.y = (b1.x & 0xff) | ((b1.y & 0xff) << 8) | ((b1.z & 0xff) << 16) | ((b1.w & 0xff) << 24);
        pb.z = (b2.x & 0xff) | ((b2.y & 0xff) << 8) | ((b2.z & 0xff) << 16) | ((b2.w & 0xff) << 24);
        pb.w = (b3.x & 0xff) | ((b3.y & 0xff) << 8) | ((b3.z & 0xff) << 16) | ((b3.w & 0xff) << 24);
        *reinterpret_cast<int4*>(As + loff) = pa;
        *reinterpret_cast<int4*>(Bs + loff) = pb;
      }
    }
    __syncthreads();  // drains vmcnt (global_load_lds) + lgkmcnt

    i32x4 af[4], bf[4];
#pragma unroll
    for (int m = 0; m < 4; ++m)
      af[m] = *reinterpret_cast<const i32x4*>(As + (wrr * 64 + m * 16 + lrow) * BK + kq * 16);
#pragma unroll
    for (int n = 0; n < 4; ++n)
      bf[n] = *reinterpret_cast<const i32x4*>(Bs + (wcc * 64 + n * 16 + lrow) * BK + kq * 16);
#pragma unroll
    for (int m = 0; m < 4; ++m)
#pragma unroll
      for (int n = 0; n < 4; ++n)
        acc[m][n] = __builtin_amdgcn_mfma_i32_16x16x64_i8(af[m], bf[n], acc[m][n], 0, 0, 0);

    __syncthreads();  // protect LDS before next-tile staging
  }

  // Epilogue: dequant -> round-half-even -> clamp -> store as float.
  // C/D layout: col = lane&15, row = (lane>>4)*4 + j (dtype-independent).
  const float scale = sx[0] * sw[0] / so[0];
#pragma unroll
  for (int m = 0; m < 4; ++m) {
#pragma unroll
    for (int n = 0; n < 4; ++n) {
#pragma unroll
      for (int j = 0; j < 4; ++j) {
        int gr = (int)arow0 + wrr * 64 + m * 16 + kq * 4 + j;
        int gc = (int)bcol0 + wcc * 64 + n * 16 + lrow;
        float v = rintf((float)acc[m][n][j] * scale);
        v = fminf(fmaxf(v, -128.f), 127.f);
        out[(size_t)gr * N_DIM + gc] = v;
      }
    }
  }
}

// ---------------------------------------------------------------------------
extern "C" void kernel_launch(void* const* d_in, const int* in_sizes, int n_in,
                              void* d_out, int out_size, void* d_ws, size_t ws_size,
                              hipStream_t stream) {
  const int* x32 = (const int*)d_in[0];
  const float* sx = (const float*)d_in[1];
  const int* w32 = (const int*)d_in[2];
  const float* sw = (const float*)d_in[3];
  const float* so = (const float*)d_in[4];
  float* out = (float*)d_out;

  tail_kernel<<<1, 1, 0, stream>>>(out, so);

  const size_t a_bytes = (size_t)M_DIM * K_DIM;
  const size_t b_bytes = (size_t)N_DIM * K_DIM;
  const int grid = (M_DIM / BM) * (N_DIM / BN);  // 64 * 32 = 2048 blocks

  if (ws_size >= a_bytes + b_bytes) {
    int8_t* A8 = (int8_t*)d_ws;
    int8_t* B8 = A8 + a_bytes;
    pack_kernel<<<2048, 256, 0, stream>>>(x32, A8, (int)(a_bytes / 4));
    pack_kernel<<<2048, 256, 0, stream>>>(w32, B8, (int)(b_bytes / 4));
    gemm_kernel<false><<<grid, 256, 0, stream>>>(A8, B8, nullptr, nullptr, out, sx, sw, so);
  } else {
    gemm_kernel<true><<<grid, 256, 0, stream>>>(nullptr, nullptr, x32, w32, out, sx, sw, so);
  }
}

// Round 6
// 401.243 us; speedup vs baseline: 1.0909x; 1.0909x over previous
//
#include <hip/hip_runtime.h>
#include <stdint.h>

#define M_DIM 8192
#define K_DIM 4096
#define N_DIM 4096

typedef __attribute__((ext_vector_type(4))) int i32x4;

// ---------------------------------------------------------------------------
// Pack int32 (values in [-128,127]) -> int8. Coalesced: 1 int4 load + 1 int
// store per thread, grid-stride. (Unchanged from R2, passing.)
// ---------------------------------------------------------------------------
__global__ __launch_bounds__(256) void pack_kernel(const int* __restrict__ src,
                                                   int8_t* __restrict__ dst,
                                                   int n4) {
  const int stride = gridDim.x * 256;
  for (int i = blockIdx.x * 256 + threadIdx.x; i < n4; i += stride) {
    int4 v = reinterpret_cast<const int4*>(src)[i];
    int p = (v.x & 0xff) | ((v.y & 0xff) << 8) |
            ((v.z & 0xff) << 16) | ((v.w & 0xff) << 24);
    reinterpret_cast<int*>(dst)[i] = p;
  }
}

__global__ void tail_kernel(float* __restrict__ out, const float* __restrict__ so) {
  out[(size_t)M_DIM * N_DIM] = so[0];
}

// ---------------------------------------------------------------------------
// 256x256 int8 GEMM, minimum 2-phase schedule (T3 catalog recipe):
//   prologue: STAGE(tile0, buf0); vmcnt(0); barrier;
//   loop kt:  STAGE(tile kt+1, buf^1); ds_read(buf); lgkmcnt(0); MFMA;
//             vmcnt(0); barrier;
// ONE vmcnt(0)+barrier per K-tile; the 8 staging loads get the entire
// 64-MFMA phase to complete. Race-free by construction (no counted vmcnt).
//
// Geometry: BM=BN=256, BK=128 B, 512 thr / 8 waves (2Mx4N), per-wave 128x64.
// LDS 2 x 64KB double buffer. st_16x32 XOR swizzle (T2): LDS dest linear
// (global_load_lds), global SOURCE col-slot pre-swizzled with ^(row&7),
// ds_read applies the same XOR -> bank-conflict-free b128 reads.
// ---------------------------------------------------------------------------
#define BM2 256
#define BN2 256
#define BK2 128
#define NT  (K_DIM / BK2)  // 32

#define ASM_VMCNT0 asm volatile("s_waitcnt vmcnt(0)" ::: "memory")
#define ASM_LGKM0  asm volatile("s_waitcnt lgkmcnt(0)" ::: "memory")
#define BARRIER()  asm volatile("s_barrier" ::: "memory")
#define SCHEDB()   __builtin_amdgcn_sched_barrier(0)

// Stage full K-tile KT (A 32KB + B 32KB) into buffer BUF. 8 loads/thread.
#define STAGE(KT, BUF) do { \
  _Pragma("unroll") \
  for (int c_ = 0; c_ < 4; ++c_) { \
    const int8_t* ga_ = A8 + (size_t)(arow0 + c_*64 + srow) * K_DIM + (size_t)(KT)*BK2 + scol; \
    __builtin_amdgcn_global_load_lds((const __attribute__((address_space(1))) void*)ga_, \
        (__attribute__((address_space(3))) void*)(lds + (BUF)*65536 + c_*8192 + tid*16), 16, 0, 0); \
  } \
  _Pragma("unroll") \
  for (int c_ = 0; c_ < 4; ++c_) { \
    const int8_t* gb_ = B8 + (size_t)(bcol0 + c_*64 + srow) * K_DIM + (size_t)(KT)*BK2 + scol; \
    __builtin_amdgcn_global_load_lds((const __attribute__((address_space(1))) void*)gb_, \
        (__attribute__((address_space(3))) void*)(lds + (BUF)*65536 + 32768 + c_*8192 + tid*16), 16, 0, 0); \
  } } while (0)

__global__ __launch_bounds__(512, 2) void gemm2p(
    const int8_t* __restrict__ A8, const int8_t* __restrict__ B8,
    float* __restrict__ out,
    const float* __restrict__ sx, const float* __restrict__ sw,
    const float* __restrict__ so) {
  __shared__ __align__(16) int8_t lds[131072];

  const int tid = threadIdx.x;
  const int lane = tid & 63;
  const int wid = tid >> 6;   // 0..7
  const int wr = wid >> 2;    // 0..1 -> 128-row strip of A
  const int wc = wid & 3;     // 0..3 -> 64-col strip of B
  const int lrow = lane & 15; // fragment row (A) / col (B)
  const int kq = lane >> 4;   // k-quarter within a 64-B k-slice

  // T1: XCD-aware bijective swizzle (512 blocks, 512 % 8 == 0).
  const int bid = blockIdx.x;
  const int wg = (bid & 7) * 64 + (bid >> 3);
  const int bm = wg & 31;   // consecutive wg share bn -> B panel L2 reuse
  const int bn = wg >> 5;
  const size_t arow0 = (size_t)bm * BM2;
  const size_t bcol0 = (size_t)bn * BN2;

  // Staging: thread t writes 16B at linear LDS offset c*8192 + t*16,
  // i.e. LDS row c*64 + (t>>3), physical col-slot t&7. Source col-slot is
  // pre-swizzled: logical = physical ^ (row&7), row&7 == (t>>3)&7.
  const int srow = tid >> 3;                               // 0..63
  const int scol = (((tid & 7) ^ ((tid >> 3) & 7)) << 4);  // bytes 0..112

  // ds_read: physical col16-slot = logical_slot ^ (row&7); row&7 == lrow&7.
  const int swz = (lrow & 7) << 4;
  const int pc0 = (0  + kq * 16) ^ swz;   // k-slice 0 (bytes 0..63)
  const int pc1 = (64 + kq * 16) ^ swz;   // k-slice 1 (bytes 64..127)
  const int aoff = (wr * 128 + lrow) * 128;         // A region base (row part)
  const int boff = 32768 + (wc * 64 + lrow) * 128;  // B region base

  i32x4 acc[8][4] = {};
  i32x4 af[8], bf[4];

  STAGE(0, 0);
  ASM_VMCNT0; BARRIER(); SCHEDB();

  for (int kt = 0; kt < NT; ++kt) {
    const int cb = kt & 1;
    const int8_t* abase = lds + cb * 65536 + aoff;
    const int8_t* bbase = lds + cb * 65536 + boff;
    if (kt < NT - 1) STAGE(kt + 1, cb ^ 1);

    // ---- k-slice 0: 12 ds_read_b128 + 32 MFMA ----
#pragma unroll
    for (int m = 0; m < 8; ++m) af[m] = *(const i32x4*)(abase + m * 2048 + pc0);
#pragma unroll
    for (int n = 0; n < 4; ++n) bf[n] = *(const i32x4*)(bbase + n * 2048 + pc0);
    ASM_LGKM0; SCHEDB();
    __builtin_amdgcn_s_setprio(1);
#pragma unroll
    for (int m = 0; m < 8; ++m)
#pragma unroll
      for (int n = 0; n < 4; ++n)
        acc[m][n] = __builtin_amdgcn_mfma_i32_16x16x64_i8(af[m], bf[n], acc[m][n], 0, 0, 0);
    __builtin_amdgcn_s_setprio(0);

    // ---- k-slice 1 ----
#pragma unroll
    for (int m = 0; m < 8; ++m) af[m] = *(const i32x4*)(abase + m * 2048 + pc1);
#pragma unroll
    for (int n = 0; n < 4; ++n) bf[n] = *(const i32x4*)(bbase + n * 2048 + pc1);
    ASM_LGKM0; SCHEDB();
    __builtin_amdgcn_s_setprio(1);
#pragma unroll
    for (int m = 0; m < 8; ++m)
#pragma unroll
      for (int n = 0; n < 4; ++n)
        acc[m][n] = __builtin_amdgcn_mfma_i32_16x16x64_i8(af[m], bf[n], acc[m][n], 0, 0, 0);
    __builtin_amdgcn_s_setprio(0);

    ASM_VMCNT0; BARRIER(); SCHEDB();  // next tile staged; buffers swap
  }

  // Epilogue: C/D layout col=lane&15, row=(lane>>4)*4+j (dtype-independent).
  const float s0 = *(volatile const float*)sx;
  const float s1 = *(volatile const float*)sw;
  const float s2 = *(volatile const float*)so;
  const float scale = s0 * s1 / s2;
#pragma unroll
  for (int m = 0; m < 8; ++m) {
#pragma unroll
    for (int n = 0; n < 4; ++n) {
#pragma unroll
      for (int j = 0; j < 4; ++j) {
        int gr = (int)arow0 + wr * 128 + m * 16 + kq * 4 + j;
        int gc = (int)bcol0 + wc * 64 + n * 16 + lrow;
        float v = rintf((float)acc[m][n][j] * scale);
        v = fminf(fmaxf(v, -128.f), 127.f);
        out[(size_t)gr * N_DIM + gc] = v;
      }
    }
  }
}

// ---------------------------------------------------------------------------
// Fallback (ws too small): proven 128x128 kernel, packs int32 in-kernel.
// ---------------------------------------------------------------------------
#define BM 128
#define BN 128
#define BK 64
__global__ __launch_bounds__(256) void gemm_direct(
    const int* __restrict__ A32, const int* __restrict__ B32,
    float* __restrict__ out,
    const float* __restrict__ sx, const float* __restrict__ sw,
    const float* __restrict__ so) {
  __shared__ int8_t As[BM * BK];
  __shared__ int8_t Bs[BN * BK];
  const int tid = threadIdx.x;
  const int lane = tid & 63;
  const int wid = tid >> 6;
  const int bid = blockIdx.x;
  const int bm = bid % (M_DIM / BM);
  const int bn = bid / (M_DIM / BM);
  const size_t arow0 = (size_t)bm * BM;
  const size_t bcol0 = (size_t)bn * BN;
  const int wrr = wid >> 1, wcc = wid & 1;
  const int lrow = lane & 15, kq = lane >> 4;
  i32x4 acc[4][4] = {};
  for (int kk = 0; kk < K_DIM; kk += BK) {
#pragma unroll
    for (int i = 0; i < 2; ++i) {
      int loff = i * 4096 + tid * 16;
      int r = loff >> 6, c = loff & 63;
      const int4* a4 = reinterpret_cast<const int4*>(A32 + (arow0 + r) * K_DIM + kk + c);
      const int4* b4 = reinterpret_cast<const int4*>(B32 + (bcol0 + r) * K_DIM + kk + c);
      int4 pa, pb;
      int4 t0 = a4[0], t1 = a4[1], t2 = a4[2], t3 = a4[3];
      pa.x = (t0.x & 0xff) | ((t0.y & 0xff) << 8) | ((t0.z & 0xff) << 16) | ((t0.w & 0xff) << 24);
      pa.y = (t1.x & 0xff) | ((t1.y & 0xff) << 8) | ((t1.z & 0xff) << 16) | ((t1.w & 0xff) << 24);
      pa.z = (t2.x & 0xff) | ((t2.y & 0xff) << 8) | ((t2.z & 0xff) << 16) | ((t2.w & 0xff) << 24);
      pa.w = (t3.x & 0xff) | ((t3.y & 0xff) << 8) | ((t3.z & 0xff) << 16) | ((t3.w & 0xff) << 24);
      t0 = b4[0]; t1 = b4[1]; t2 = b4[2]; t3 = b4[3];
      pb.x = (t0.x & 0xff) | ((t0.y & 0xff) << 8) | ((t0.z & 0xff) << 16) | ((t0.w & 0xff) << 24);
      pb.y = (t1.x & 0xff) | ((t1.y & 0xff) << 8) | ((t1.z & 0xff) << 16) | ((t1.w & 0xff) << 24);
      pb.z = (t2.x & 0xff) | ((t2.y & 0xff) << 8) | ((t2.z & 0xff) << 16) | ((t2.w & 0xff) << 24);
      pb.w = (t3.x & 0xff) | ((t3.y & 0xff) << 8) | ((t3.z & 0xff) << 16) | ((t3.w & 0xff) << 24);
      *reinterpret_cast<int4*>(As + loff) = pa;
      *reinterpret_cast<int4*>(Bs + loff) = pb;
    }
    __syncthreads();
    i32x4 afr[4], bfr[4];
#pragma unroll
    for (int m = 0; m < 4; ++m)
      afr[m] = *reinterpret_cast<const i32x4*>(As + (wrr * 64 + m * 16 + lrow) * BK + kq * 16);
#pragma unroll
    for (int n = 0; n < 4; ++n)
      bfr[n] = *reinterpret_cast<const i32x4*>(Bs + (wcc * 64 + n * 16 + lrow) * BK + kq * 16);
#pragma unroll
    for (int m = 0; m < 4; ++m)
#pragma unroll
      for (int n = 0; n < 4; ++n)
        acc[m][n] = __builtin_amdgcn_mfma_i32_16x16x64_i8(afr[m], bfr[n], acc[m][n], 0, 0, 0);
    __syncthreads();
  }
  const float scale = sx[0] * sw[0] / so[0];
#pragma unroll
  for (int m = 0; m < 4; ++m)
#pragma unroll
    for (int n = 0; n < 4; ++n)
#pragma unroll
      for (int j = 0; j < 4; ++j) {
        int gr = (int)arow0 + wrr * 64 + m * 16 + kq * 4 + j;
        int gc = (int)bcol0 + wcc * 64 + n * 16 + lrow;
        float v = rintf((float)acc[m][n][j] * scale);
        v = fminf(fmaxf(v, -128.f), 127.f);
        out[(size_t)gr * N_DIM + gc] = v;
      }
}

// ---------------------------------------------------------------------------
extern "C" void kernel_launch(void* const* d_in, const int* in_sizes, int n_in,
                              void* d_out, int out_size, void* d_ws, size_t ws_size,
                              hipStream_t stream) {
  const int* x32 = (const int*)d_in[0];
  const float* sx = (const float*)d_in[1];
  const int* w32 = (const int*)d_in[2];
  const float* sw = (const float*)d_in[3];
  const float* so = (const float*)d_in[4];
  float* out = (float*)d_out;

  tail_kernel<<<1, 1, 0, stream>>>(out, so);

  const size_t a_bytes = (size_t)M_DIM * K_DIM;
  const size_t b_bytes = (size_t)N_DIM * K_DIM;

  if (ws_size >= a_bytes + b_bytes) {
    int8_t* A8 = (int8_t*)d_ws;
    int8_t* B8 = A8 + a_bytes;
    pack_kernel<<<2048, 256, 0, stream>>>(x32, A8, (int)(a_bytes / 4));
    pack_kernel<<<2048, 256, 0, stream>>>(w32, B8, (int)(b_bytes / 4));
    const int grid = (M_DIM / BM2) * (N_DIM / BN2);  // 512
    gemm2p<<<grid, 512, 0, stream>>>(A8, B8, out, sx, sw, so);
  } else {
    const int grid = (M_DIM / BM) * (N_DIM / BN);
    gemm_direct<<<grid, 256, 0, stream>>>(x32, w32, out, sx, sw, so);
  }
}

// Round 7
// 399.889 us; speedup vs baseline: 1.0946x; 1.0034x over previous
//
#include <hip/hip_runtime.h>
#include <stdint.h>

#define M_DIM 8192
#define K_DIM 4096
#define N_DIM 4096

typedef __attribute__((ext_vector_type(4))) int i32x4;

// ---------------------------------------------------------------------------
// Pack int32 (values in [-128,127]) -> int8. (Unchanged, passing.)
// ---------------------------------------------------------------------------
__global__ __launch_bounds__(256) void pack_kernel(const int* __restrict__ src,
                                                   int8_t* __restrict__ dst,
                                                   int n4) {
  const int stride = gridDim.x * 256;
  for (int i = blockIdx.x * 256 + threadIdx.x; i < n4; i += stride) {
    int4 v = reinterpret_cast<const int4*>(src)[i];
    int p = (v.x & 0xff) | ((v.y & 0xff) << 8) |
            ((v.z & 0xff) << 16) | ((v.w & 0xff) << 24);
    reinterpret_cast<int*>(dst)[i] = p;
  }
}

__global__ void tail_kernel(float* __restrict__ out, const float* __restrict__ so) {
  out[(size_t)M_DIM * N_DIM] = so[0];
}

// ---------------------------------------------------------------------------
// 256x256 int8 GEMM, 4-phase counted-vmcnt schedule (honest per-half ledger).
//
// Key fix vs the R3 race: each wave's output rows/cols are SPLIT across both
// halves of the tile: A row = mh*128 + wr*64 + m*16, B col = nh*128 + wc*32
// + n*16. Quadrant (mh,nh) therefore consumes EXACTLY half-tiles A(mh),B(nh).
//
// Stage order (tile t+1, during tile t): P1:Alo  P2:Blo  P3:Bhi  P4:Ahi
// Consume order (tile t):                P1:Alo+Blo  P2:Bhi  P3:Ahi  P4:-
// Ledger (2 global_load_lds per half, per wave):
//   P1 entry: outstanding {Alo,Blo,Bhi,Ahi}(t)=8 -> vmcnt(4) drains Alo,Blo
//   P2 entry: outstanding {Bhi,Ahi}(t)+{Alo}(t+1)=6 -> vmcnt(4) drains Bhi
//   P3 entry: outstanding {Ahi}(t)+{Alo,Blo}(t+1)=6 -> vmcnt(4) drains Ahi
//   P4: no data need. Never drains below 4 in the loop.
// Peeled last tile: vmcnt(4) / (2) / (0). Per-wave vmcnt + s_barrier per
// phase = all-wave completion before any ds_read of that half.
// Buffer WAR: stage of half X(t+1) into buf pb is >=1 barrier after the last
// read of that region (tile t-1's phase) -- safe.
// ---------------------------------------------------------------------------
#define BM2 256
#define BN2 256
#define BK2 128
#define NT  (K_DIM / BK2)  // 32

#define ASM_VMCNT(N) asm volatile("s_waitcnt vmcnt(" #N ")" ::: "memory")
#define ASM_LGKM0    asm volatile("s_waitcnt lgkmcnt(0)" ::: "memory")
#define BARRIER()    asm volatile("s_barrier" ::: "memory")
#define SCHEDB()     __builtin_amdgcn_sched_barrier(0)

// Stage one A/B half-tile (128 rows x 128B = 16KB) of K-tile KT into BUF.
// 2 loads/thread. LDS dest linear; global source col pre-swizzled (scol).
#define STAGE_A(KT, H, BUF) do { \
  _Pragma("unroll") \
  for (int c_ = 0; c_ < 2; ++c_) { \
    const int8_t* g_ = A8 + (size_t)(arow0 + (H)*128 + c_*64 + srow) * K_DIM + (size_t)(KT)*BK2 + scol; \
    __builtin_amdgcn_global_load_lds((const __attribute__((address_space(1))) void*)g_, \
        (__attribute__((address_space(3))) void*)(lds + (BUF)*65536 + (H)*16384 + c_*8192 + tid*16), 16, 0, 0); \
  } } while (0)

#define STAGE_B(KT, H, BUF) do { \
  _Pragma("unroll") \
  for (int c_ = 0; c_ < 2; ++c_) { \
    const int8_t* g_ = B8 + (size_t)(bcol0 + (H)*128 + c_*64 + srow) * K_DIM + (size_t)(KT)*BK2 + scol; \
    __builtin_amdgcn_global_load_lds((const __attribute__((address_space(1))) void*)g_, \
        (__attribute__((address_space(3))) void*)(lds + (BUF)*65536 + 32768 + (H)*16384 + c_*8192 + tid*16), 16, 0, 0); \
  } } while (0)

// ds_read fragments: A half MH (4 rows x 2 k-slices = 8 b128), B half NH (4).
#define READ_AF(MH, AB) do { \
  _Pragma("unroll") \
  for (int m_ = 0; m_ < 4; ++m_) { \
    const int8_t* p_ = (AB) + (MH)*16384 + m_*2048; \
    af[(MH)*4 + m_][0] = *(const i32x4*)(p_ + pc0); \
    af[(MH)*4 + m_][1] = *(const i32x4*)(p_ + pc1); \
  } } while (0)

#define READ_BF(NH, BB) do { \
  _Pragma("unroll") \
  for (int n_ = 0; n_ < 2; ++n_) { \
    const int8_t* p_ = (BB) + (NH)*16384 + n_*2048; \
    bf[(NH)*2 + n_][0] = *(const i32x4*)(p_ + pc0); \
    bf[(NH)*2 + n_][1] = *(const i32x4*)(p_ + pc1); \
  } } while (0)

// Quadrant MFMA: 4m x 2n x 2k = 16 MFMA, setprio-wrapped (T5).
#define MMA16(MH, NH) do { \
  __builtin_amdgcn_s_setprio(1); \
  _Pragma("unroll") \
  for (int m_ = 0; m_ < 4; ++m_) \
    _Pragma("unroll") \
    for (int n_ = 0; n_ < 2; ++n_) { \
      acc[(MH)*4 + m_][(NH)*2 + n_] = __builtin_amdgcn_mfma_i32_16x16x64_i8( \
          af[(MH)*4 + m_][0], bf[(NH)*2 + n_][0], acc[(MH)*4 + m_][(NH)*2 + n_], 0, 0, 0); \
      acc[(MH)*4 + m_][(NH)*2 + n_] = __builtin_amdgcn_mfma_i32_16x16x64_i8( \
          af[(MH)*4 + m_][1], bf[(NH)*2 + n_][1], acc[(MH)*4 + m_][(NH)*2 + n_], 0, 0, 0); \
    } \
  __builtin_amdgcn_s_setprio(0); \
} while (0)

__global__ __launch_bounds__(512, 2) void gemm8p(
    const int8_t* __restrict__ A8, const int8_t* __restrict__ B8,
    float* __restrict__ out,
    const float* __restrict__ sx, const float* __restrict__ sw,
    const float* __restrict__ so) {
  __shared__ __align__(16) int8_t lds[131072];

  const int tid = threadIdx.x;
  const int lane = tid & 63;
  const int wid = tid >> 6;   // 0..7
  const int wr = wid >> 2;    // 0..1 -> 64-row sub-strip within each A half
  const int wc = wid & 3;     // 0..3 -> 32-col sub-strip within each B half
  const int lrow = lane & 15;
  const int kq = lane >> 4;

  // T1: XCD-aware bijective swizzle (512 blocks, 512 % 8 == 0).
  const int bid = blockIdx.x;
  const int wg = (bid & 7) * 64 + (bid >> 3);
  const int bm = wg & 31;
  const int bn = wg >> 5;
  const size_t arow0 = (size_t)bm * BM2;
  const size_t bcol0 = (size_t)bn * BN2;

  // Staging addressing (per half-tile): row-in-half = c*64 + (tid>>3),
  // physical col-slot tid&7; source col-slot = physical ^ (row&7).
  const int srow = tid >> 3;
  const int scol = (((tid & 7) ^ ((tid >> 3) & 7)) << 4);

  // ds_read: physical col16-slot = logical ^ (lrow&7).
  const int swz = (lrow & 7) << 4;
  const int pc0 = (0  + kq * 16) ^ swz;
  const int pc1 = (64 + kq * 16) ^ swz;
  const int aoff = (wr * 64 + lrow) * 128;          // A base (within half 0)
  const int boff = 32768 + (wc * 32 + lrow) * 128;  // B base

  i32x4 acc[8][4] = {};
  i32x4 af[8][2], bf[4][2];

  // Prologue: stage tile 0 in ledger order.
  STAGE_A(0, 0, 0); STAGE_B(0, 0, 0); STAGE_B(0, 1, 0); STAGE_A(0, 1, 0);

  for (int kt = 0; kt < NT - 1; ++kt) {
    const int cb = kt & 1;
    const int pb = cb ^ 1;
    const int8_t* ab = lds + cb * 65536 + aoff;
    const int8_t* bb = lds + cb * 65536 + boff;
    // P1: needs Alo(kt), Blo(kt)
    ASM_VMCNT(4); BARRIER(); SCHEDB();
    READ_AF(0, ab); READ_BF(0, bb);
    STAGE_A(kt + 1, 0, pb);
    ASM_LGKM0; SCHEDB();
    MMA16(0, 0);
    // P2: needs Bhi(kt)
    ASM_VMCNT(4); BARRIER(); SCHEDB();
    READ_BF(1, bb);
    STAGE_B(kt + 1, 0, pb);
    ASM_LGKM0; SCHEDB();
    MMA16(0, 1);
    // P3: needs Ahi(kt)
    ASM_VMCNT(4); BARRIER(); SCHEDB();
    READ_AF(1, ab);
    STAGE_B(kt + 1, 1, pb);
    ASM_LGKM0; SCHEDB();
    MMA16(1, 0);
    // P4: register-only
    BARRIER(); SCHEDB();
    STAGE_A(kt + 1, 1, pb);
    MMA16(1, 1);
  }
  {  // Peeled last tile (cb = (NT-1)&1): no staging; drain 4 -> 2 -> 0.
    const int cb = (NT - 1) & 1;
    const int8_t* ab = lds + cb * 65536 + aoff;
    const int8_t* bb = lds + cb * 65536 + boff;
    ASM_VMCNT(4); BARRIER(); SCHEDB();
    READ_AF(0, ab); READ_BF(0, bb);
    ASM_LGKM0; SCHEDB();
    MMA16(0, 0);
    ASM_VMCNT(2); BARRIER(); SCHEDB();
    READ_BF(1, bb);
    ASM_LGKM0; SCHEDB();
    MMA16(0, 1);
    ASM_VMCNT(0); BARRIER(); SCHEDB();
    READ_AF(1, ab);
    ASM_LGKM0; SCHEDB();
    MMA16(1, 0);
    MMA16(1, 1);
  }

  // Epilogue. acc[am][bn]: row = (am>>2)*128 + wr*64 + (am&3)*16 + kq*4 + j,
  //                        col = (bn>>1)*128 + wc*32 + (bn&1)*16 + lrow.
  const float s0 = *(volatile const float*)sx;
  const float s1 = *(volatile const float*)sw;
  const float s2 = *(volatile const float*)so;
  const float scale = s0 * s1 / s2;
#pragma unroll
  for (int am = 0; am < 8; ++am) {
#pragma unroll
    for (int bn2 = 0; bn2 < 4; ++bn2) {
#pragma unroll
      for (int j = 0; j < 4; ++j) {
        int gr = (int)arow0 + (am >> 2) * 128 + wr * 64 + (am & 3) * 16 + kq * 4 + j;
        int gc = (int)bcol0 + (bn2 >> 1) * 128 + wc * 32 + (bn2 & 1) * 16 + lrow;
        float v = rintf((float)acc[am][bn2][j] * scale);
        v = fminf(fmaxf(v, -128.f), 127.f);
        out[(size_t)gr * N_DIM + gc] = v;
      }
    }
  }
}

// ---------------------------------------------------------------------------
// Fallback (ws too small): proven 128x128 kernel, packs int32 in-kernel.
// ---------------------------------------------------------------------------
#define BM 128
#define BN 128
#define BK 64
__global__ __launch_bounds__(256) void gemm_direct(
    const int* __restrict__ A32, const int* __restrict__ B32,
    float* __restrict__ out,
    const float* __restrict__ sx, const float* __restrict__ sw,
    const float* __restrict__ so) {
  __shared__ int8_t As[BM * BK];
  __shared__ int8_t Bs[BN * BK];
  const int tid = threadIdx.x;
  const int lane = tid & 63;
  const int wid = tid >> 6;
  const int bid = blockIdx.x;
  const int bm = bid % (M_DIM / BM);
  const int bn = bid / (M_DIM / BM);
  const size_t arow0 = (size_t)bm * BM;
  const size_t bcol0 = (size_t)bn * BN;
  const int wrr = wid >> 1, wcc = wid & 1;
  const int lrow = lane & 15, kq = lane >> 4;
  i32x4 acc[4][4] = {};
  for (int kk = 0; kk < K_DIM; kk += BK) {
#pragma unroll
    for (int i = 0; i < 2; ++i) {
      int loff = i * 4096 + tid * 16;
      int r = loff >> 6, c = loff & 63;
      const int4* a4 = reinterpret_cast<const int4*>(A32 + (arow0 + r) * K_DIM + kk + c);
      const int4* b4 = reinterpret_cast<const int4*>(B32 + (bcol0 + r) * K_DIM + kk + c);
      int4 pa, pb;
      int4 t0 = a4[0], t1 = a4[1], t2 = a4[2], t3 = a4[3];
      pa.x = (t0.x & 0xff) | ((t0.y & 0xff) << 8) | ((t0.z & 0xff) << 16) | ((t0.w & 0xff) << 24);
      pa.y = (t1.x & 0xff) | ((t1.y & 0xff) << 8) | ((t1.z & 0xff) << 16) | ((t1.w & 0xff) << 24);
      pa.z = (t2.x & 0xff) | ((t2.y & 0xff) << 8) | ((t2.z & 0xff) << 16) | ((t2.w & 0xff) << 24);
      pa.w = (t3.x & 0xff) | ((t3.y & 0xff) << 8) | ((t3.z & 0xff) << 16) | ((t3.w & 0xff) << 24);
      t0 = b4[0]; t1 = b4[1]; t2 = b4[2]; t3 = b4[3];
      pb.x = (t0.x & 0xff) | ((t0.y & 0xff) << 8) | ((t0.z & 0xff) << 16) | ((t0.w & 0xff) << 24);
      pb.y = (t1.x & 0xff) | ((t1.y & 0xff) << 8) | ((t1.z & 0xff) << 16) | ((t1.w & 0xff) << 24);
      pb.z = (t2.x & 0xff) | ((t2.y & 0xff) << 8) | ((t2.z & 0xff) << 16) | ((t2.w & 0xff) << 24);
      pb.w = (t3.x & 0xff) | ((t3.y & 0xff) << 8) | ((t3.z & 0xff) << 16) | ((t3.w & 0xff) << 24);
      *reinterpret_cast<int4*>(As + loff) = pa;
      *reinterpret_cast<int4*>(Bs + loff) = pb;
    }
    __syncthreads();
    i32x4 afr[4], bfr[4];
#pragma unroll
    for (int m = 0; m < 4; ++m)
      afr[m] = *reinterpret_cast<const i32x4*>(As + (wrr * 64 + m * 16 + lrow) * BK + kq * 16);
#pragma unroll
    for (int n = 0; n < 4; ++n)
      bfr[n] = *reinterpret_cast<const i32x4*>(Bs + (wcc * 64 + n * 16 + lrow) * BK + kq * 16);
#pragma unroll
    for (int m = 0; m < 4; ++m)
#pragma unroll
      for (int n = 0; n < 4; ++n)
        acc[m][n] = __builtin_amdgcn_mfma_i32_16x16x64_i8(afr[m], bfr[n], acc[m][n], 0, 0, 0);
    __syncthreads();
  }
  const float scale = sx[0] * sw[0] / so[0];
#pragma unroll
  for (int m = 0; m < 4; ++m)
#pragma unroll
    for (int n = 0; n < 4; ++n)
#pragma unroll
      for (int j = 0; j < 4; ++j) {
        int gr = (int)arow0 + wrr * 64 + m * 16 + kq * 4 + j;
        int gc = (int)bcol0 + wcc * 64 + n * 16 + lrow;
        float v = rintf((float)acc[m][n][j] * scale);
        v = fminf(fmaxf(v, -128.f), 127.f);
        out[(size_t)gr * N_DIM + gc] = v;
      }
}

// ---------------------------------------------------------------------------
extern "C" void kernel_launch(void* const* d_in, const int* in_sizes, int n_in,
                              void* d_out, int out_size, void* d_ws, size_t ws_size,
                              hipStream_t stream) {
  const int* x32 = (const int*)d_in[0];
  const float* sx = (const float*)d_in[1];
  const int* w32 = (const int*)d_in[2];
  const float* sw = (const float*)d_in[3];
  const float* so = (const float*)d_in[4];
  float* out = (float*)d_out;

  tail_kernel<<<1, 1, 0, stream>>>(out, so);

  const size_t a_bytes = (size_t)M_DIM * K_DIM;
  const size_t b_bytes = (size_t)N_DIM * K_DIM;

  if (ws_size >= a_bytes + b_bytes) {
    int8_t* A8 = (int8_t*)d_ws;
    int8_t* B8 = A8 + a_bytes;
    pack_kernel<<<2048, 256, 0, stream>>>(x32, A8, (int)(a_bytes / 4));
    pack_kernel<<<2048, 256, 0, stream>>>(w32, B8, (int)(b_bytes / 4));
    const int grid = (M_DIM / BM2) * (N_DIM / BN2);  // 512
    gemm8p<<<grid, 512, 0, stream>>>(A8, B8, out, sx, sw, so);
  } else {
    const int grid = (M_DIM / BM) * (N_DIM / BN);
    gemm_direct<<<grid, 256, 0, stream>>>(x32, w32, out, sx, sw, so);
  }
}